// Round 4
// baseline (142.467 us; speedup 1.0000x reference)
//
#include <hip/hip_runtime.h>
#include <hip/hip_bf16.h>
#include <cmath>

#define B_   4
#define NT_  2048
#define G_   4096
#define DZ_  128

typedef __attribute__((ext_vector_type(8))) short bf16x8;
typedef __attribute__((ext_vector_type(4))) float f32x4;

__device__ __forceinline__ float softplus_f(float x) {
    return fmaxf(x, 0.0f) + log1pf(expf(-fabsf(x)));
}

// async 16B global -> LDS (lane i lands at ldst + 16*i)
__device__ __forceinline__ void gl2lds16(const void* gsrc, void* ldst) {
    __builtin_amdgcn_global_load_lds(
        (const __attribute__((address_space(1))) unsigned int*)gsrc,
        (__attribute__((address_space(3))) unsigned int*)ldst, 16, 0, 0);
}

// z_grid (B,G,DZ) fp32 -> Zt (B,DZ,G) bf16 (RNE); also builds per-g table
// table[b*G+g] = (gx, gy, U0, U1),  Uk = c[0][k]*gx^2 + c[1][k]*gy^2
__global__ __launch_bounds__(256, 1)
void transpose_z(const float* __restrict__ z, const float* __restrict__ xg,
                 const float* __restrict__ lsp,
                 unsigned short* __restrict__ zt, float4* __restrict__ table)
{
    __shared__ unsigned short tile[64][66];
    const int bx = blockIdx.x;                // 4b * 64gt * 2zt = 512
    const int zti = bx & 1;
    const int gt  = (bx >> 1) & 63;
    const int b   = bx >> 7;
    const int g0 = gt * 64, z0 = zti * 64;
    const int tid = threadIdx.x;
    const int zl = tid & 63, gl = tid >> 6;
    #pragma unroll
    for (int i = 0; i < 16; ++i) {
        const int g = gl + i * 4;
        const float v = z[(size_t)(b * G_ + g0 + g) * DZ_ + z0 + zl];
        unsigned int u = __float_as_uint(v);
        u = u + 0x7FFFu + ((u >> 16) & 1u);   // RNE to bf16
        tile[g][zl] = (unsigned short)(u >> 16);
    }
    if (zti == 0 && tid < 64) {               // per-g coefficient table
        const float h = -0.72134752f;         // -0.5*log2(e)
        float ls;
        ls = 1e-5f + softplus_f(lsp[0]); const float c00 = h / (ls * ls);
        ls = 1e-5f + softplus_f(lsp[1]); const float c01 = h / (ls * ls);
        ls = 1e-5f + softplus_f(lsp[2]); const float c10 = h / (ls * ls);
        ls = 1e-5f + softplus_f(lsp[3]); const float c11 = h / (ls * ls);
        const int g = g0 + tid;
        const float gx = xg[(size_t)(b * G_ + g) * 2 + 0];
        const float gy = xg[(size_t)(b * G_ + g) * 2 + 1];
        table[(size_t)b * G_ + g] = make_float4(
            gx, gy, c00 * gx * gx + c10 * gy * gy, c01 * gx * gx + c11 * gy * gy);
    }
    __syncthreads();
    const int gp = (tid & 31) * 2, zi = tid >> 5;
    #pragma unroll
    for (int i = 0; i < 8; ++i) {
        const int zz = zi + i * 8;
        const unsigned int lo = tile[gp][zz], hi = tile[gp + 1][zz];
        *(unsigned int*)(zt + (size_t)(b * DZ_ + z0 + zz) * G_ + g0 + gp)
            = lo | (hi << 16);
    }
}

// Block = (b, 16 t-rows) x full 128 z x full 4096 g.  8 waves:
//  - producer role: wave w computes weights for kernel kk=w>>2, K-half sW=(w>>1)&1,
//    col-half sub=w&1 (4 exps/lane/chunk) -> A-layout LDS (double-buffered)
//  - consumer role: wave w MFMA-consumes z-slice [w*16, w*16+16) for both kk
// Each (t,g,k) weight computed exactly once grid-wide.
__global__ __launch_bounds__(512, 4)
void setconv_main(const float* __restrict__ xt,
                  const float* __restrict__ lsp,
                  const unsigned short* __restrict__ Zt,
                  const float4* __restrict__ table,
                  float* __restrict__ out)
{
    __shared__ unsigned short lds[20480];     // 40 KB: Z 2x8192, W 2x2048 (ushorts)

    const int bx = blockIdx.x;                // 512 = b*128 + tt
    const int tt = bx & 127;
    const int b  = bx >> 7;
    const int tid  = threadIdx.x;
    const int w    = tid >> 6;
    const int lane = tid & 63;
    const int quad = lane >> 4;
    const int l15  = lane & 15;
    const int t0   = tt * 16;

    const int kk  = w >> 2;                   // producer kernel idx
    const int sW  = (w >> 1) & 1;             // producer K-half (g 0..31 / 32..63)
    const int sub = w & 1;                    // producer col-half
    const int R   = w >> 1;                   // A row-block = kk*2+sW

    const float h = -0.72134752f;
    float ls;
    ls = 1e-5f + softplus_f(lsp[0]); const float c00 = h / (ls * ls);
    ls = 1e-5f + softplus_f(lsp[1]); const float c01 = h / (ls * ls);
    ls = 1e-5f + softplus_f(lsp[2]); const float c10 = h / (ls * ls);
    ls = 1e-5f + softplus_f(lsp[3]); const float c11 = h / (ls * ls);
    const float cx = kk ? c01 : c00;
    const float cy = kk ? c11 : c10;

    // per-lane t constants (t-row = t0 + l15)
    const float xt0 = xt[(size_t)(b * NT_ + t0 + l15) * 2 + 0];
    const float xt1 = xt[(size_t)(b * NT_ + t0 + l15) * 2 + 1];
    const float At  = cx * xt0 * xt0 + cy * xt1 * xt1;
    const float nP0 = -2.0f * cx * xt0;
    const float nP1 = -2.0f * cy * xt1;

    f32x4 acc0 = (f32x4)0.0f, acc1 = (f32x4)0.0f;

    unsigned short* const zbuf0 = lds;
    unsigned short* const zbuf1 = lds + 8192;
    unsigned short* const wbuf0 = lds + 16384;
    unsigned short* const wbuf1 = lds + 18432;

    // Z staging: wave w stages z-rows [w*16, w*16+16), XOR-swizzled chunks
    const int r8 = lane >> 3, c8 = lane & 7, gc = c8 ^ r8;
    const unsigned short* gz = Zt + (size_t)(b * DZ_ + w * 16 + r8) * G_ + gc * 8;
    const int swz = l15 & 7;

    // producer table base: g_local = sW*32 + sub*16 + quad*4 (+j)
    const float4* tp = table + (size_t)b * G_ + sW * 32 + sub * 16 + quad * 4;
    const int wofs = (R * 16 + l15) * 32 + sub * 16 + quad * 4;  // ushort idx

    // ---- prologue: stage + produce chunk 0 into buf0 ----
    {
        gl2lds16(gz,          zbuf0 + (w * 16) * 64);
        gl2lds16(gz + 8 * G_, zbuf0 + (w * 16 + 8) * 64);
        unsigned int wb[4];
        #pragma unroll
        for (int j = 0; j < 4; ++j) {
            const float4 tv = tp[j];
            const float U = kk ? tv.w : tv.z;
            const float e = fmaf(tv.y, nP1, fmaf(tv.x, nP0, At + U));
            wb[j] = __float_as_uint(__builtin_amdgcn_exp2f(e));
        }
        const unsigned int u0 = __builtin_amdgcn_perm(wb[1], wb[0], 0x07060302u);
        const unsigned int u1 = __builtin_amdgcn_perm(wb[3], wb[2], 0x07060302u);
        *(uint2*)(wbuf0 + wofs) = make_uint2(u0, u1);
        __syncthreads();
    }

    #pragma unroll 2
    for (int ch = 0; ch < 64; ++ch) {
        unsigned short* const zc = (ch & 1) ? zbuf1 : zbuf0;
        unsigned short* const wc = (ch & 1) ? wbuf1 : wbuf0;
        unsigned short* const zn = (ch & 1) ? zbuf0 : zbuf1;
        unsigned short* const wn = (ch & 1) ? wbuf0 : wbuf1;

        if (ch < 63) {
            // async Z stage for ch+1
            const unsigned short* s = gz + (size_t)(ch + 1) * 64;
            gl2lds16(s,          zn + (w * 16) * 64);
            gl2lds16(s + 8 * G_, zn + (w * 16 + 8) * 64);
            // produce weights for ch+1
            unsigned int wb[4];
            #pragma unroll
            for (int j = 0; j < 4; ++j) {
                const float4 tv = tp[(ch + 1) * 64 + j];
                const float U = kk ? tv.w : tv.z;
                const float e = fmaf(tv.y, nP1, fmaf(tv.x, nP0, At + U));
                wb[j] = __float_as_uint(__builtin_amdgcn_exp2f(e));
            }
            const unsigned int u0 = __builtin_amdgcn_perm(wb[1], wb[0], 0x07060302u);
            const unsigned int u1 = __builtin_amdgcn_perm(wb[3], wb[2], 0x07060302u);
            *(uint2*)(wn + wofs) = make_uint2(u0, u1);
        }

        // consume chunk ch: 2 K=32 groups, both kernels, own 16-z slice
        #pragma unroll
        for (int s = 0; s < 2; ++s) {
            const bf16x8 bz = *(const bf16x8*)(zc + (w * 16 + l15) * 64
                                               + (((s * 4 + quad) ^ swz) * 8));
            const bf16x8 a0 = *(const bf16x8*)(wc + ((s    ) * 16 + l15) * 32 + quad * 8);
            const bf16x8 a1 = *(const bf16x8*)(wc + ((2 + s) * 16 + l15) * 32 + quad * 8);
            acc0 = __builtin_amdgcn_mfma_f32_16x16x32_bf16(a0, bz, acc0, 0, 0, 0);
            acc1 = __builtin_amdgcn_mfma_f32_16x16x32_bf16(a1, bz, acc1, 0, 0, 0);
        }
        __syncthreads();
    }

    // epilogue: C/D layout row(m=t)=quad*4+r, col(n=z)=l15; pack (kk0,kk1)
    const int tr = t0 + quad * 4;
    float* ob = out + (size_t)(b * NT_ + tr) * (DZ_ * 2) + (w * 16 + l15) * 2;
    #pragma unroll
    for (int r = 0; r < 4; ++r)
        *(float2*)(ob + (size_t)r * (DZ_ * 2)) = make_float2(acc0[r], acc1[r]);
}

extern "C" void kernel_launch(void* const* d_in, const int* in_sizes, int n_in,
                              void* d_out, int out_size, void* d_ws, size_t ws_size,
                              hipStream_t stream)
{
    const float* x_grid = (const float*)d_in[0];   // (4,64,64,2)
    const float* z_grid = (const float*)d_in[1];   // (4,64,64,128)
    const float* xt     = (const float*)d_in[2];   // (4,2048,2)
    const float* lsp    = (const float*)d_in[3];   // (2,2)
    float* out = (float*)d_out;                    // (4,2048,256) fp32

    unsigned short* Zt = (unsigned short*)d_ws;                    // 4 MB
    float4* table = (float4*)((char*)d_ws + (size_t)B_ * DZ_ * G_ * 2);  // 256 KB

    hipLaunchKernelGGL(transpose_z, dim3(512), dim3(256), 0, stream,
                       z_grid, x_grid, lsp, Zt, table);
    hipLaunchKernelGGL(setconv_main, dim3(512), dim3(512), 0, stream,
                       xt, lsp, Zt, table, out);
}

// Round 5
// 139.244 us; speedup vs baseline: 1.0231x; 1.0231x over previous
//
#include <hip/hip_runtime.h>
#include <hip/hip_bf16.h>
#include <cmath>

#define B_   4
#define NT_  2048
#define G_   4096
#define DZ_  128

typedef __attribute__((ext_vector_type(8))) short bf16x8;
typedef __attribute__((ext_vector_type(4))) float f32x4;

__device__ __forceinline__ float softplus_f(float x) {
    return fmaxf(x, 0.0f) + log1pf(expf(-fabsf(x)));
}

// z_grid (B,G,DZ) fp32 -> Zt (B,DZ,G) bf16 (RNE), packed-uint stores
__global__ __launch_bounds__(256, 1)
void transpose_z(const float* __restrict__ z, unsigned short* __restrict__ zt)
{
    __shared__ unsigned short tile[64][66];
    const int bx = blockIdx.x;                // 4b * 64gt * 2zt = 512
    const int zti = bx & 1;
    const int gt  = (bx >> 1) & 63;
    const int b   = bx >> 7;
    const int g0 = gt * 64, z0 = zti * 64;
    const int tid = threadIdx.x;
    const int zl = tid & 63, gl = tid >> 6;
    #pragma unroll
    for (int i = 0; i < 16; ++i) {
        const int g = gl + i * 4;
        const float v = z[(size_t)(b * G_ + g0 + g) * DZ_ + z0 + zl];
        unsigned int u = __float_as_uint(v);
        u = u + 0x7FFFu + ((u >> 16) & 1u);   // RNE to bf16
        tile[g][zl] = (unsigned short)(u >> 16);
    }
    __syncthreads();
    const int gp = (tid & 31) * 2, zi = tid >> 5;
    #pragma unroll
    for (int i = 0; i < 8; ++i) {
        const int zz = zi + i * 8;
        const unsigned int lo = tile[gp][zz], hi = tile[gp + 1][zz];
        *(unsigned int*)(zt + (size_t)(b * DZ_ + z0 + zz) * G_ + g0 + gp)
            = lo | (hi << 16);
    }
}

// Block = (b, 16 t) x 128 z x 4096 g.  8 waves = 8-way k-split (512 g each).
// A (weights) in-register; B (Zt) read directly from global (L2-resident);
// no LDS / no barriers in the main loop.  Epilogue: 3-round LDS k-reduction.
__global__ __launch_bounds__(512, 4)
void setconv_main(const float* __restrict__ xt,
                  const float* __restrict__ xg,
                  const float* __restrict__ lsp,
                  const unsigned short* __restrict__ Zt,
                  float* __restrict__ out)
{
    __shared__ float red[16384];              // 64 KB: 4 slots x 16 planes x 256 f

    // XCD swizzle: bx = tt2*8 + b*2 + p  ->  same-b blocks share 2 XCDs
    const int bx = blockIdx.x;
    const int b  = (bx >> 1) & 3;
    const int tt = ((bx >> 3) << 1) | (bx & 1);   // 0..127
    const int tid  = threadIdx.x;
    const int w    = tid >> 6;                // = kh, 0..7
    const int lane = tid & 63;
    const int quad = lane >> 4;
    const int l15  = lane & 15;
    const int t0   = tt * 16;

    float c00, c01, c10, c11;
    {
        const float h = -0.72134752f;         // -0.5*log2(e)
        float ls;
        ls = 1e-5f + softplus_f(lsp[0]); c00 = h / (ls * ls);
        ls = 1e-5f + softplus_f(lsp[1]); c01 = h / (ls * ls);
        ls = 1e-5f + softplus_f(lsp[2]); c10 = h / (ls * ls);
        ls = 1e-5f + softplus_f(lsp[3]); c11 = h / (ls * ls);
    }

    // A-frag row m = l15 -> per-lane t constants
    const float xt0 = xt[(size_t)(b * NT_ + t0 + l15) * 2 + 0];
    const float xt1 = xt[(size_t)(b * NT_ + t0 + l15) * 2 + 1];

    f32x4 acc[2][8];
    #pragma unroll
    for (int k = 0; k < 2; ++k)
        #pragma unroll
        for (int n = 0; n < 8; ++n) acc[k][n] = (f32x4)0.0f;

    const int g0 = w * 512;                   // this wave's k-range
    // B-frag base: z-row = l15 (+nt*16), g = g0 + quad*8 (+ch*32)
    const unsigned short* zb = Zt + (size_t)(b * DZ_ + l15) * G_ + g0 + quad * 8;
    const float* xgp = xg + (size_t)(b * G_ + g0 + quad * 8) * 2;

    #pragma unroll 2
    for (int ch = 0; ch < 16; ++ch) {
        // B-frags nt 0..3 (issue early; latency hides under weight math)
        bf16x8 bzA[4];
        #pragma unroll
        for (int nt = 0; nt < 4; ++nt)
            bzA[nt] = *(const bf16x8*)(zb + (size_t)nt * 16 * G_ + ch * 32);
        // xg for this quad's 8 g-slots
        const float* xp = xgp + ch * 64;
        const float4 xv0 = *(const float4*)(xp + 0);
        const float4 xv1 = *(const float4*)(xp + 4);
        const float4 xv2 = *(const float4*)(xp + 8);
        const float4 xv3 = *(const float4*)(xp + 12);
        float gx[8], gy[8];
        gx[0]=xv0.x; gy[0]=xv0.y; gx[1]=xv0.z; gy[1]=xv0.w;
        gx[2]=xv1.x; gy[2]=xv1.y; gx[3]=xv1.z; gy[3]=xv1.w;
        gx[4]=xv2.x; gy[4]=xv2.y; gx[5]=xv2.z; gy[5]=xv2.w;
        gx[6]=xv3.x; gy[6]=xv3.y; gx[7]=xv3.z; gy[7]=xv3.w;
        unsigned int w0b[8], w1b[8];
        #pragma unroll
        for (int j = 0; j < 8; ++j) {
            const float d0 = xt0 - gx[j];
            const float d1 = xt1 - gy[j];
            const float q0 = d0 * d0;
            const float q1 = d1 * d1;
            const float e0 = fmaf(q1, c10, q0 * c00);
            const float e1 = fmaf(q1, c11, q0 * c01);
            w0b[j] = __float_as_uint(__builtin_amdgcn_exp2f(e0));
            w1b[j] = __float_as_uint(__builtin_amdgcn_exp2f(e1));
        }
        union { bf16x8 v; unsigned int u[4]; } a0, a1;
        #pragma unroll
        for (int h = 0; h < 4; ++h) {
            a0.u[h] = __builtin_amdgcn_perm(w0b[2*h+1], w0b[2*h], 0x07060302u);
            a1.u[h] = __builtin_amdgcn_perm(w1b[2*h+1], w1b[2*h], 0x07060302u);
        }
        // B-frags nt 4..7
        bf16x8 bzB[4];
        #pragma unroll
        for (int nt = 0; nt < 4; ++nt)
            bzB[nt] = *(const bf16x8*)(zb + (size_t)(nt + 4) * 16 * G_ + ch * 32);
        #pragma unroll
        for (int nt = 0; nt < 4; ++nt) {
            acc[0][nt] = __builtin_amdgcn_mfma_f32_16x16x32_bf16(a0.v, bzA[nt], acc[0][nt], 0, 0, 0);
            acc[1][nt] = __builtin_amdgcn_mfma_f32_16x16x32_bf16(a1.v, bzA[nt], acc[1][nt], 0, 0, 0);
        }
        #pragma unroll
        for (int nt = 0; nt < 4; ++nt) {
            acc[0][nt+4] = __builtin_amdgcn_mfma_f32_16x16x32_bf16(a0.v, bzB[nt], acc[0][nt+4], 0, 0, 0);
            acc[1][nt+4] = __builtin_amdgcn_mfma_f32_16x16x32_bf16(a1.v, bzB[nt], acc[1][nt+4], 0, 0, 0);
        }
    }

    // ---- 3-round k-reduction over the 8 kh-waves ----
    // slot s: 16 planes (p = kk*8+nt) of 64 lanes x f32x4, contiguous -> conflict-free
    #define RED_W(slot) { \
        float* bp = &red[(slot) * 4096 + lane * 4]; \
        _Pragma("unroll") \
        for (int k = 0; k < 2; ++k) \
            _Pragma("unroll") \
            for (int n = 0; n < 8; ++n) \
                *(f32x4*)(bp + (k * 8 + n) * 256) = acc[k][n]; }
    #define RED_A(slot) { \
        const float* bp = &red[(slot) * 4096 + lane * 4]; \
        _Pragma("unroll") \
        for (int k = 0; k < 2; ++k) \
            _Pragma("unroll") \
            for (int n = 0; n < 8; ++n) \
                acc[k][n] += *(const f32x4*)(bp + (k * 8 + n) * 256); }

    if (w >= 4) RED_W(w - 4);
    __syncthreads();
    if (w < 4) RED_A(w);
    if (w == 2 || w == 3) RED_W(w);
    __syncthreads();
    if (w < 2) RED_A(w + 2);
    if (w == 1) RED_W(3);
    __syncthreads();
    if (w == 0) {
        RED_A(3);
        const int tr = t0 + quad * 4;
        #pragma unroll
        for (int nt = 0; nt < 8; ++nt) {
            float* ob = out + (size_t)(b * NT_ + tr) * (DZ_ * 2) + (nt * 16 + l15) * 2;
            #pragma unroll
            for (int r = 0; r < 4; ++r)
                *(float2*)(ob + (size_t)r * (DZ_ * 2)) =
                    make_float2(acc[0][nt][r], acc[1][nt][r]);
        }
    }
    #undef RED_W
    #undef RED_A
}

extern "C" void kernel_launch(void* const* d_in, const int* in_sizes, int n_in,
                              void* d_out, int out_size, void* d_ws, size_t ws_size,
                              hipStream_t stream)
{
    const float* x_grid = (const float*)d_in[0];   // (4,64,64,2)
    const float* z_grid = (const float*)d_in[1];   // (4,64,64,128)
    const float* xt     = (const float*)d_in[2];   // (4,2048,2)
    const float* lsp    = (const float*)d_in[3];   // (2,2)
    float* out = (float*)d_out;                    // (4,2048,256) fp32
    unsigned short* Zt = (unsigned short*)d_ws;    // (4,128,4096) bf16 = 4 MB

    hipLaunchKernelGGL(transpose_z, dim3(512), dim3(256), 0, stream, z_grid, Zt);
    hipLaunchKernelGGL(setconv_main, dim3(512), dim3(512), 0, stream,
                       xt, x_grid, lsp, Zt, out);
}

// Round 6
// 111.075 us; speedup vs baseline: 1.2826x; 1.2536x over previous
//
#include <hip/hip_runtime.h>
#include <hip/hip_bf16.h>
#include <cmath>

#define B_   4
#define NT_  2048
#define G_   4096
#define DZ_  128

typedef __attribute__((ext_vector_type(8))) short bf16x8;
typedef __attribute__((ext_vector_type(4))) float f32x4;

__device__ __forceinline__ float softplus_f(float x) {
    return fmaxf(x, 0.0f) + log1pf(expf(-fabsf(x)));
}

// z_grid (B,G,DZ) fp32 -> Zt2 tiled bf16: Zt2[((b*128 + c)*128 + z)*32 + gi],
// c = g>>5, gi = g&31.  B-fragments become contiguous 1 KB bursts.
__global__ __launch_bounds__(256, 1)
void transpose_z(const float* __restrict__ z, unsigned short* __restrict__ zt)
{
    __shared__ unsigned short tile[64][66];
    const int bx = blockIdx.x;                // 4b * 64gt * 2zt = 512
    const int zti = bx & 1;
    const int gt  = (bx >> 1) & 63;
    const int b   = bx >> 7;
    const int g0 = gt * 64, z0 = zti * 64;
    const int tid = threadIdx.x;
    const int zl = tid & 63, gl = tid >> 6;
    #pragma unroll
    for (int i = 0; i < 16; ++i) {
        const int g = gl + i * 4;
        const float v = z[(size_t)(b * G_ + g0 + g) * DZ_ + z0 + zl];
        unsigned int u = __float_as_uint(v);
        u = u + 0x7FFFu + ((u >> 16) & 1u);   // RNE to bf16
        tile[g][zl] = (unsigned short)(u >> 16);
    }
    __syncthreads();
    const int gp = (tid & 31) * 2, zi = tid >> 5;
    const int c  = (g0 + gp) >> 5, gi = gp & 31;
    #pragma unroll
    for (int i = 0; i < 8; ++i) {
        const int zz = zi + i * 8;
        const unsigned int lo = tile[gp][zz], hi = tile[gp + 1][zz];
        *(unsigned int*)(zt + ((size_t)(b * 128 + c) * 128 + z0 + zz) * 32 + gi)
            = lo | (hi << 16);
    }
}

// Block = (b, 16 t) x 128 z x 4096 g.  8 waves = 8-way k-split (512 g each).
// A (weights) in-register; B (Zt2, tiled) read directly from L2; no main-loop
// LDS/barriers.  Epilogue: 3-round LDS k-reduction.
__global__ __launch_bounds__(512, 4)
void setconv_main(const float* __restrict__ xt,
                  const float* __restrict__ xg,
                  const float* __restrict__ lsp,
                  const unsigned short* __restrict__ Zt,
                  float* __restrict__ out)
{
    __shared__ float red[16384];              // 64 KB: 4 slots x 16 planes x 256 f

    // XCD swizzle: bx = tt2*8 + b*2 + p -> same-b blocks share 2 XCDs
    const int bx = blockIdx.x;
    const int b  = (bx >> 1) & 3;
    const int tt = ((bx >> 3) << 1) | (bx & 1);   // 0..127
    const int tid  = threadIdx.x;
    const int w    = tid >> 6;                // = kh, 0..7
    const int lane = tid & 63;
    const int quad = lane >> 4;
    const int l15  = lane & 15;
    const int t0   = tt * 16;

    float c00, c01, c10, c11;
    {
        const float h = -0.72134752f;         // -0.5*log2(e)
        float ls;
        ls = 1e-5f + softplus_f(lsp[0]); c00 = h / (ls * ls);
        ls = 1e-5f + softplus_f(lsp[1]); c01 = h / (ls * ls);
        ls = 1e-5f + softplus_f(lsp[2]); c10 = h / (ls * ls);
        ls = 1e-5f + softplus_f(lsp[3]); c11 = h / (ls * ls);
    }

    // A-frag row m = l15 -> per-lane t constants
    const float xt0 = xt[(size_t)(b * NT_ + t0 + l15) * 2 + 0];
    const float xt1 = xt[(size_t)(b * NT_ + t0 + l15) * 2 + 1];

    f32x4 acc[2][8];
    #pragma unroll
    for (int k = 0; k < 2; ++k)
        #pragma unroll
        for (int n = 0; n < 8; ++n) acc[k][n] = (f32x4)0.0f;

    const int g0 = w * 512;                   // this wave's k-range
    // tiled B base: chunk c = w*16 + ch, z-row = nt*16 + l15, gi = quad*8
    const unsigned short* zb = Zt + ((size_t)(b * 128 + w * 16) * 128 + l15) * 32
                               + quad * 8;
    const float* xgp = xg + (size_t)(b * G_ + g0 + quad * 8) * 2;

    #pragma unroll 2
    for (int ch = 0; ch < 16; ++ch) {
        // B-frags nt 0..3 (contiguous 1 KB per instr)
        bf16x8 bzA[4];
        #pragma unroll
        for (int nt = 0; nt < 4; ++nt)
            bzA[nt] = *(const bf16x8*)(zb + (size_t)ch * 4096 + nt * 512);
        // xg for this quad's 8 g-slots
        const float* xp = xgp + ch * 64;
        const float4 xv0 = *(const float4*)(xp + 0);
        const float4 xv1 = *(const float4*)(xp + 4);
        const float4 xv2 = *(const float4*)(xp + 8);
        const float4 xv3 = *(const float4*)(xp + 12);
        float gx[8], gy[8];
        gx[0]=xv0.x; gy[0]=xv0.y; gx[1]=xv0.z; gy[1]=xv0.w;
        gx[2]=xv1.x; gy[2]=xv1.y; gx[3]=xv1.z; gy[3]=xv1.w;
        gx[4]=xv2.x; gy[4]=xv2.y; gx[5]=xv2.z; gy[5]=xv2.w;
        gx[6]=xv3.x; gy[6]=xv3.y; gx[7]=xv3.z; gy[7]=xv3.w;
        unsigned int w0b[8], w1b[8];
        #pragma unroll
        for (int j = 0; j < 8; ++j) {
            const float d0 = xt0 - gx[j];
            const float d1 = xt1 - gy[j];
            const float q0 = d0 * d0;
            const float q1 = d1 * d1;
            const float e0 = fmaf(q1, c10, q0 * c00);
            const float e1 = fmaf(q1, c11, q0 * c01);
            w0b[j] = __float_as_uint(__builtin_amdgcn_exp2f(e0));
            w1b[j] = __float_as_uint(__builtin_amdgcn_exp2f(e1));
        }
        union { bf16x8 v; unsigned int u[4]; } a0, a1;
        #pragma unroll
        for (int h = 0; h < 4; ++h) {
            a0.u[h] = __builtin_amdgcn_perm(w0b[2*h+1], w0b[2*h], 0x07060302u);
            a1.u[h] = __builtin_amdgcn_perm(w1b[2*h+1], w1b[2*h], 0x07060302u);
        }
        // B-frags nt 4..7
        bf16x8 bzB[4];
        #pragma unroll
        for (int nt = 0; nt < 4; ++nt)
            bzB[nt] = *(const bf16x8*)(zb + (size_t)ch * 4096 + (nt + 4) * 512);
        #pragma unroll
        for (int nt = 0; nt < 4; ++nt) {
            acc[0][nt] = __builtin_amdgcn_mfma_f32_16x16x32_bf16(a0.v, bzA[nt], acc[0][nt], 0, 0, 0);
            acc[1][nt] = __builtin_amdgcn_mfma_f32_16x16x32_bf16(a1.v, bzA[nt], acc[1][nt], 0, 0, 0);
        }
        #pragma unroll
        for (int nt = 0; nt < 4; ++nt) {
            acc[0][nt+4] = __builtin_amdgcn_mfma_f32_16x16x32_bf16(a0.v, bzB[nt], acc[0][nt+4], 0, 0, 0);
            acc[1][nt+4] = __builtin_amdgcn_mfma_f32_16x16x32_bf16(a1.v, bzB[nt], acc[1][nt+4], 0, 0, 0);
        }
    }

    // ---- 3-round k-reduction over the 8 kh-waves ----
    #define RED_W(slot) { \
        float* bp = &red[(slot) * 4096 + lane * 4]; \
        _Pragma("unroll") \
        for (int k = 0; k < 2; ++k) \
            _Pragma("unroll") \
            for (int n = 0; n < 8; ++n) \
                *(f32x4*)(bp + (k * 8 + n) * 256) = acc[k][n]; }
    #define RED_A(slot) { \
        const float* bp = &red[(slot) * 4096 + lane * 4]; \
        _Pragma("unroll") \
        for (int k = 0; k < 2; ++k) \
            _Pragma("unroll") \
            for (int n = 0; n < 8; ++n) \
                acc[k][n] += *(const f32x4*)(bp + (k * 8 + n) * 256); }

    if (w >= 4) RED_W(w - 4);
    __syncthreads();
    if (w < 4) RED_A(w);
    if (w == 2 || w == 3) RED_W(w);
    __syncthreads();
    if (w < 2) RED_A(w + 2);
    if (w == 1) RED_W(3);
    __syncthreads();
    if (w == 0) {
        RED_A(3);
        const int tr = t0 + quad * 4;
        #pragma unroll
        for (int nt = 0; nt < 8; ++nt) {
            float* ob = out + (size_t)(b * NT_ + tr) * (DZ_ * 2) + (nt * 16 + l15) * 2;
            #pragma unroll
            for (int r = 0; r < 4; ++r)
                *(float2*)(ob + (size_t)r * (DZ_ * 2)) =
                    make_float2(acc[0][nt][r], acc[1][nt][r]);
        }
    }
    #undef RED_W
    #undef RED_A
}

extern "C" void kernel_launch(void* const* d_in, const int* in_sizes, int n_in,
                              void* d_out, int out_size, void* d_ws, size_t ws_size,
                              hipStream_t stream)
{
    const float* x_grid = (const float*)d_in[0];   // (4,64,64,2)
    const float* z_grid = (const float*)d_in[1];   // (4,64,64,128)
    const float* xt     = (const float*)d_in[2];   // (4,2048,2)
    const float* lsp    = (const float*)d_in[3];   // (2,2)
    float* out = (float*)d_out;                    // (4,2048,256) fp32
    unsigned short* Zt = (unsigned short*)d_ws;    // tiled, 4 MB

    hipLaunchKernelGGL(transpose_z, dim3(512), dim3(256), 0, stream, z_grid, Zt);
    hipLaunchKernelGGL(setconv_main, dim3(512), dim3(512), 0, stream,
                       xt, x_grid, lsp, Zt, out);
}